// Round 2
// baseline (451.894 us; speedup 1.0000x reference)
//
#include <hip/hip_runtime.h>

// x: (32, 2, 513, 2048) fp32. Row = (b, f): 2048 elems.
// noise = mean of 32 smallest mag^2; out[b,0,f,:] = relu(mag-noise)*cos(ph),
// out[b,1,f,:] = relu(mag-noise)*sin(ph).
//
// One wave (64 lanes) per row, 32 elems/lane in registers. Exact k=32 select
// via 31-iteration binary search on uint bit patterns (sq >= 0 so uint order
// == float order). No LDS, no barriers.

#define NROWS      16416          // 32*513
#define HALF_PLANE (513 * 2048)   // stride between channel 0 and 1

typedef float v4f __attribute__((ext_vector_type(4)));

__global__ __launch_bounds__(256, 4) void spectral_sub_kernel(
    const float* __restrict__ x, float* __restrict__ out) {
  const int lane = threadIdx.x & 63;
  const int waveInBlock = threadIdx.x >> 6;
  const int row = blockIdx.x * 4 + waveInBlock;   // grid covers exactly NROWS

  const int b = row / 513;
  const int f = row - b * 513;
  const size_t base = ((size_t)b * 2 * 513 + (size_t)f) * 2048;

  const float* magp = x + base;
  const float* php  = x + base + HALF_PLANE;

  // ---- load 32 mags/lane, coalesced 16B ----
  float mag[32];
  float sq[32];
#pragma unroll
  for (int j = 0; j < 8; ++j) {
    const v4f v = *(const v4f*)(magp + j * 256 + lane * 4);
    mag[4 * j + 0] = v.x;
    mag[4 * j + 1] = v.y;
    mag[4 * j + 2] = v.z;
    mag[4 * j + 3] = v.w;
  }
#pragma unroll
  for (int i = 0; i < 32; ++i) sq[i] = mag[i] * mag[i];

  // ---- binary search for the 32nd smallest sq (bit pattern T) ----
  // Invariant: answer's bits above `bit` equal T's. count(key < cand) >= 32
  // => answer < cand => bit stays 0; else bit is 1.
  unsigned T = 0;
#pragma unroll 1
  for (int bit = 30; bit >= 0; --bit) {
    const unsigned cand = T | (1u << bit);
    int c = 0;
#pragma unroll
    for (int i = 0; i < 32; ++i) c += (__float_as_uint(sq[i]) < cand) ? 1 : 0;
#pragma unroll
    for (int off = 32; off; off >>= 1) c += __shfl_xor(c, off, 64);
    if (c < 32) T = cand;
  }

  // ---- exact sum of the 32 smallest: strict-below + ties at T ----
  const float Tf = __uint_as_float(T);
  float ssum = 0.0f;
  int cb = 0;
#pragma unroll
  for (int i = 0; i < 32; ++i) {
    if (__float_as_uint(sq[i]) < T) {
      ssum += sq[i];
      cb += 1;
    }
  }
#pragma unroll
  for (int off = 32; off; off >>= 1) {
    ssum += __shfl_xor(ssum, off, 64);
    cb += __shfl_xor(cb, off, 64);
  }
  const float noise = (ssum + (float)(32 - cb) * Tf) * (1.0f / 32.0f);

  // ---- epilogue: relu(mag - noise) * {cos,sin}(phase), streamed out ----
  float* orp = out + base;               // channel 0: real
  float* oip = out + base + HALF_PLANE;  // channel 1: imag
#pragma unroll
  for (int j = 0; j < 8; ++j) {
    const v4f ph = *(const v4f*)(php + j * 256 + lane * 4);
    v4f re, im;
    float s, c, m;

    m = fmaxf(mag[4 * j + 0] - noise, 0.0f);
    __sincosf(ph.x, &s, &c);
    re.x = m * c; im.x = m * s;

    m = fmaxf(mag[4 * j + 1] - noise, 0.0f);
    __sincosf(ph.y, &s, &c);
    re.y = m * c; im.y = m * s;

    m = fmaxf(mag[4 * j + 2] - noise, 0.0f);
    __sincosf(ph.z, &s, &c);
    re.z = m * c; im.z = m * s;

    m = fmaxf(mag[4 * j + 3] - noise, 0.0f);
    __sincosf(ph.w, &s, &c);
    re.w = m * c; im.w = m * s;

    __builtin_nontemporal_store(re, (v4f*)(orp + j * 256 + lane * 4));
    __builtin_nontemporal_store(im, (v4f*)(oip + j * 256 + lane * 4));
  }
}

extern "C" void kernel_launch(void* const* d_in, const int* in_sizes, int n_in,
                              void* d_out, int out_size, void* d_ws, size_t ws_size,
                              hipStream_t stream) {
  const float* x = (const float*)d_in[0];
  float* out = (float*)d_out;
  // n_avg (d_in[1]) is a compile-time constant 32 per the reference.
  const int blocks = NROWS / 4;  // 4 rows (waves) per 256-thread block
  spectral_sub_kernel<<<blocks, 256, 0, stream>>>(x, out);
}

// Round 3
// 449.745 us; speedup vs baseline: 1.0048x; 1.0048x over previous
//
#include <hip/hip_runtime.h>

// x: (32, 2, 513, 2048) fp32. Row = (b, f): 2048 elems.
// noise = mean of 32 smallest mag^2; out[b,0] = relu(mag-noise)*cos(ph),
// out[b,1] = relu(mag-noise)*sin(ph).
//
// One wave per row, 32 mags/lane in registers. k=32 order statistic found by
// 16-step MSB-first binary search on the bit pattern of |mag| (uint order ==
// float order for non-negative floats; 32 smallest |m| == 32 smallest m^2).
// Per-step wave-wide count via __ballot + scalar-pipe popcount — no shuffle
// chains, no LDS. Truncation to bit 15 leaves <=2^-8 relative error on the
// threshold => ~2e-6 absolute noise error (threshold is 0.104).

#define NROWS      16416          // 32*513
#define HALF_PLANE (513 * 2048)   // stride between channel 0 and 1
#define LOWBIT     15             // search bits 30..LOWBIT (16 iterations)

typedef float v4f __attribute__((ext_vector_type(4)));

__global__ __launch_bounds__(256, 8) void spectral_sub_kernel(
    const float* __restrict__ x, float* __restrict__ out) {
  const int lane = threadIdx.x & 63;
  const int waveInBlock = threadIdx.x >> 6;
  const int row = blockIdx.x * 4 + waveInBlock;   // grid covers exactly NROWS

  const int b = row / 513;
  const int f = row - b * 513;
  const size_t base = ((size_t)b * 2 * 513 + (size_t)f) * 2048;

  const float* magp = x + base;
  const float* php  = x + base + HALF_PLANE;

  // ---- load 32 mags/lane, coalesced 16B ----
  float mag[32];
#pragma unroll
  for (int j = 0; j < 8; ++j) {
    const v4f v = *(const v4f*)(magp + j * 256 + lane * 4);
    mag[4 * j + 0] = v.x;
    mag[4 * j + 1] = v.y;
    mag[4 * j + 2] = v.z;
    mag[4 * j + 3] = v.w;
  }

  // ---- binary search for the 32nd smallest |mag| (bit pattern T) ----
  // Invariant: count(|m| < T) < 32. Count per candidate via ballot+popcount:
  // one v_cmp (abs modifier is free) + scalar bcnt/add per element.
  unsigned T = 0;
#pragma unroll 1
  for (int bit = 30; bit >= LOWBIT; --bit) {
    const unsigned cand = T | (1u << bit);
    const float candf = __uint_as_float(cand);
    int c = 0;
#pragma unroll
    for (int i = 0; i < 32; ++i)
      c += __builtin_popcountll(__ballot(fabsf(mag[i]) < candf));
    if (c < 32) T = cand;
  }

  // ---- sum of squares strictly below T; ties filled with midpoint^2 ----
  const float Tf = __uint_as_float(T);
  float ssum = 0.0f;
  int cb = 0;
#pragma unroll
  for (int i = 0; i < 32; ++i) {
    const bool below = fabsf(mag[i]) < Tf;
    cb += __builtin_popcountll(__ballot(below));
    const float m = below ? mag[i] : 0.0f;
    ssum = fmaf(m, m, ssum);
  }
#pragma unroll
  for (int off = 32; off; off >>= 1) ssum += __shfl_xor(ssum, off, 64);

  const float Tmid = __uint_as_float(T + (1u << (LOWBIT - 1)));
  const float noise = (ssum + (float)(32 - cb) * (Tmid * Tmid)) * (1.0f / 32.0f);

  // ---- epilogue: relu(mag - noise) * {cos,sin}(phase), streamed out ----
  float* orp = out + base;               // channel 0: real
  float* oip = out + base + HALF_PLANE;  // channel 1: imag
#pragma unroll
  for (int j = 0; j < 8; ++j) {
    const v4f ph = *(const v4f*)(php + j * 256 + lane * 4);
    v4f re, im;
    float s, c, m;

    m = fmaxf(mag[4 * j + 0] - noise, 0.0f);
    __sincosf(ph.x, &s, &c);
    re.x = m * c; im.x = m * s;

    m = fmaxf(mag[4 * j + 1] - noise, 0.0f);
    __sincosf(ph.y, &s, &c);
    re.y = m * c; im.y = m * s;

    m = fmaxf(mag[4 * j + 2] - noise, 0.0f);
    __sincosf(ph.z, &s, &c);
    re.z = m * c; im.z = m * s;

    m = fmaxf(mag[4 * j + 3] - noise, 0.0f);
    __sincosf(ph.w, &s, &c);
    re.w = m * c; im.w = m * s;

    __builtin_nontemporal_store(re, (v4f*)(orp + j * 256 + lane * 4));
    __builtin_nontemporal_store(im, (v4f*)(oip + j * 256 + lane * 4));
  }
}

extern "C" void kernel_launch(void* const* d_in, const int* in_sizes, int n_in,
                              void* d_out, int out_size, void* d_ws, size_t ws_size,
                              hipStream_t stream) {
  const float* x = (const float*)d_in[0];
  float* out = (float*)d_out;
  // n_avg (d_in[1]) is a compile-time constant 32 per the reference.
  const int blocks = NROWS / 4;  // 4 rows (waves) per 256-thread block
  spectral_sub_kernel<<<blocks, 256, 0, stream>>>(x, out);
}